// Round 1
// baseline (610.804 us; speedup 1.0000x reference)
//
#include <hip/hip_runtime.h>
#include <cstdint>
#include <cstddef>

// Problem dims (fixed)
#define TOK   1024   // B*T
#define DIMX  512
#define HID   2048
#define DM    256
#define GENH  512
#define RR    64
#define O3BASE 65536 // start row of path-3 block in gen_w2 (2*R*DIM)

typedef __bf16 bf16x8 __attribute__((ext_vector_type(8)));
typedef float  f32x4  __attribute__((ext_vector_type(4)));

__device__ __forceinline__ unsigned short f2bf(float f) {
  union { float f; uint32_t u; } v; v.f = f;
  return (unsigned short)((v.u + 0x7fffu + ((v.u >> 16) & 1u)) >> 16);
}
__device__ __forceinline__ float bf2f(unsigned short h) {
  union { uint32_t u; float f; } v; v.u = (uint32_t)h << 16;
  return v.f;
}
__device__ __forceinline__ float silu_f(float x) { return x / (1.f + __expf(-x)); }

__device__ __forceinline__ void async_copy16(const void* g, void* l) {
  __builtin_amdgcn_global_load_lds(
      (const __attribute__((address_space(1))) void*)g,
      (__attribute__((address_space(3))) void*)l, 16, 0, 0);
}

// ---------------------------------------------------------------------------
// Core: C[128 x 128] tile of A(bf16, row-major, K-contig) @ B(f32, row-major,
// K-contig)^T via mfma_f32_16x16x32_bf16. 4 waves in 2x2. XOR-swizzled LDS
// chunk placement (chunk' = chunk ^ (row&7)) -> 2-way-max bank aliasing (free).
// A staged with global_load_lds width=16 (bf16 in ws); B converted f32->bf16.
// Ends with __syncthreads() so caller may reuse As/Bs.
// ---------------------------------------------------------------------------
template<int KLEN>
__device__ __forceinline__ void mfma_tile_nt(
    const unsigned short* __restrict__ Abf, size_t a_row0, int astride,
    const float* __restrict__ Bf, size_t b_row0, int bstride, int k0,
    unsigned short* As, unsigned short* Bs, f32x4 (&acc)[4][4]) {
  const int tid  = threadIdx.x;
  const int lane = tid & 63;
  const int wave = tid >> 6;
  const int m0 = (wave >> 1) * 64, n0 = (wave & 1) * 64;

  for (int kk = 0; kk < KLEN; kk += 64) {
    // ---- stage A: 16KB via global_load_lds, lane i -> base + i*16 (HW) ----
#pragma unroll
    for (int j = 0; j < 4; ++j) {
      int s   = wave * 256 + j * 64 + lane;   // linear 16B slot 0..1023
      int row = s >> 3;
      int kc  = (s & 7) ^ (row & 7);          // fetch-side swizzle
      const unsigned short* g =
          Abf + (a_row0 + (size_t)row) * (size_t)astride + k0 + kk + kc * 8;
      async_copy16(g, (char*)As + wave * 4096 + j * 1024);
    }
    // ---- stage B: f32 -> bf16 convert, swizzled ds_write ----
#pragma unroll
    for (int i = 0; i < 4; ++i) {
      int q = i * 256 + tid;                  // 16B-out chunk 0..1023
      int row = q >> 3, c = q & 7;
      const float* src = Bf + (b_row0 + (size_t)row) * (size_t)bstride + k0 + kk + c * 8;
      float4 v0 = *(const float4*)src;
      float4 v1 = *(const float4*)(src + 4);
      ushort4 h0, h1;
      h0.x = f2bf(v0.x); h0.y = f2bf(v0.y); h0.z = f2bf(v0.z); h0.w = f2bf(v0.w);
      h1.x = f2bf(v1.x); h1.y = f2bf(v1.y); h1.z = f2bf(v1.z); h1.w = f2bf(v1.w);
      unsigned short* dst = Bs + row * 64 + (c ^ (row & 7)) * 8;
      *(ushort4*)dst       = h0;
      *(ushort4*)(dst + 4) = h1;
    }
    __syncthreads();
    // ---- compute: 2 x (16 MFMA) on the 64-wide K slab ----
#pragma unroll
    for (int ks = 0; ks < 2; ++ks) {
      int cbase = ks * 4 + (lane >> 4);
      int koff  = (cbase ^ (lane & 7)) * 8;   // row&7 == lane&7 for all frags
      bf16x8 a[4], b[4];
#pragma unroll
      for (int mf = 0; mf < 4; ++mf)
        a[mf] = *(const bf16x8*)(As + (m0 + mf * 16 + (lane & 15)) * 64 + koff);
#pragma unroll
      for (int nf = 0; nf < 4; ++nf)
        b[nf] = *(const bf16x8*)(Bs + (n0 + nf * 16 + (lane & 15)) * 64 + koff);
#pragma unroll
      for (int mf = 0; mf < 4; ++mf)
#pragma unroll
        for (int nf = 0; nf < 4; ++nf)
          acc[mf][nf] = __builtin_amdgcn_mfma_f32_16x16x32_bf16(
              a[mf], b[nf], acc[mf][nf], 0, 0, 0);
    }
    __syncthreads();
  }
}

__device__ __forceinline__ void zero_acc(f32x4 (&acc)[4][4]) {
#pragma unroll
  for (int i = 0; i < 4; ++i)
#pragma unroll
    for (int j = 0; j < 4; ++j) {
      f32x4 z = {0.f, 0.f, 0.f, 0.f};
      acc[i][j] = z;
    }
}

// ---------------------------------------------------------------------------
// prep: hg = silu(m_tok @ gen_w1^T + gen_b1) -> bf16; x -> bf16. 4 tokens/blk.
// ---------------------------------------------------------------------------
__global__ __launch_bounds__(256) void prep_kernel(
    const float* __restrict__ x, const float* __restrict__ m_tok,
    const float* __restrict__ gen_w1, const float* __restrict__ gen_b1,
    unsigned short* __restrict__ xb, unsigned short* __restrict__ hgb) {
  __shared__ float mt[4 * DM];
  const int tid = threadIdx.x;
  const size_t t0 = (size_t)blockIdx.x * 4;
#pragma unroll
  for (int k = 0; k < 4; ++k) mt[k * 256 + tid] = m_tok[t0 * DM + k * 256 + tid];
#pragma unroll
  for (int k = 0; k < 8; ++k) {
    size_t idx = t0 * DIMX + k * 256 + tid;
    xb[idx] = f2bf(x[idx]);
  }
  __syncthreads();
#pragma unroll
  for (int hh = 0; hh < 2; ++hh) {
    int h = hh * 256 + tid;
    float a0, a1, a2, a3;
    a0 = a1 = a2 = a3 = gen_b1[h];
    const float* wr = gen_w1 + (size_t)h * DM;
    for (int d = 0; d < DM; d += 4) {
      float4 w = *(const float4*)(wr + d);
      a0 += w.x * mt[d]       + w.y * mt[d + 1]       + w.z * mt[d + 2]       + w.w * mt[d + 3];
      a1 += w.x * mt[256 + d] + w.y * mt[256 + d + 1] + w.z * mt[256 + d + 2] + w.w * mt[256 + d + 3];
      a2 += w.x * mt[512 + d] + w.y * mt[512 + d + 1] + w.z * mt[512 + d + 2] + w.w * mt[512 + d + 3];
      a3 += w.x * mt[768 + d] + w.y * mt[768 + d + 1] + w.z * mt[768 + d + 2] + w.w * mt[768 + d + 3];
    }
    hgb[(t0 + 0) * GENH + h] = f2bf(silu_f(a0));
    hgb[(t0 + 1) * GENH + h] = f2bf(silu_f(a1));
    hgb[(t0 + 2) * GENH + h] = f2bf(silu_f(a2));
    hgb[(t0 + 3) * GENH + h] = f2bf(silu_f(a3));
  }
}

// ---------------------------------------------------------------------------
// Generic NT GEMM: C[tok, N] = A_bf16[tok, KFULL] @ B_f32[N, KFULL]^T + bias.
// SPLIT: grid.y splits K, atomicAdd into pre-zeroed C (bias from k-slice 0).
// ---------------------------------------------------------------------------
template<int N, int KFULL, int KTILE, bool SPLIT>
__global__ __launch_bounds__(256) void gemm_nt_kernel(
    const unsigned short* __restrict__ A, const float* __restrict__ B,
    const float* __restrict__ bias, float* __restrict__ C) {
  __shared__ unsigned short As[8192];
  __shared__ unsigned short Bs[8192];
  constexpr int NB = N / 128;
  const int ob = blockIdx.x % NB, tb = blockIdx.x / NB;
  const size_t o0 = (size_t)ob * 128, t0 = (size_t)tb * 128;
  const int k0 = SPLIT ? blockIdx.y * KTILE : 0;
  f32x4 acc[4][4];
  zero_acc(acc);
  mfma_tile_nt<KTILE>(A, t0, KFULL, B, o0, KFULL, k0, As, Bs, acc);

  const int tid = threadIdx.x, lane = tid & 63, wave = tid >> 6;
  const int m0 = (wave >> 1) * 64, n0 = (wave & 1) * 64;
#pragma unroll
  for (int nf = 0; nf < 4; ++nf) {
    int n = n0 + nf * 16 + (lane & 15);
    float bv = (!SPLIT || k0 == 0) ? bias[o0 + n] : 0.f;
#pragma unroll
    for (int mf = 0; mf < 4; ++mf) {
      int mb = m0 + mf * 16 + ((lane >> 4) << 2);
#pragma unroll
      for (int rg = 0; rg < 4; ++rg) {
        size_t idx = (t0 + mb + rg) * (size_t)N + o0 + n;
        float v = acc[mf][nf][rg] + bv;
        if (SPLIT) atomicAdd(&C[idx], v);
        else C[idx] = v;
      }
    }
  }
}

// ---------------------------------------------------------------------------
// h_base = bf16(silu(x1) * x2)
// ---------------------------------------------------------------------------
__global__ void silu_mul_kernel(const float* __restrict__ a,
                                const float* __restrict__ b,
                                unsigned short* __restrict__ o) {
  size_t i = (size_t)blockIdx.x * 256 + threadIdx.x;
  o[i] = f2bf(silu_f(a[i]) * b[i]);
}

// ---------------------------------------------------------------------------
// memuv: fused paths 1&2. Block = [128 tok x 128 o] tile of w (o in one r),
// epilogue contracts against x (bf16, LDS pad-132 -> conflict-free) and
// shuffle-reduces to u[t, j] (j = 0..127: u1 r | u2 r). gen_b2 folded in.
// ---------------------------------------------------------------------------
union SmemUV {
  struct { unsigned short As[8192], Bs[8192]; } ab;
  struct { unsigned short Xs[128 * 132]; float upart[128]; } ep;
};

__global__ __launch_bounds__(256) void memuv_kernel(
    const unsigned short* __restrict__ hgb, const float* __restrict__ gen_w2,
    const float* __restrict__ gen_b2, const unsigned short* __restrict__ xb,
    float* __restrict__ u) {
  __shared__ SmemUV sm;
  const int bx = blockIdx.x;
  const int ob = bx & 511, tb = bx >> 9;
  const size_t o0 = (size_t)ob * 128, t0 = (size_t)tb * 128;
  const int j  = ob >> 2;           // u column (0..127)
  const int d0 = (ob & 3) * 128;    // d-range within the r row

  f32x4 acc[4][4];
  zero_acc(acc);
  mfma_tile_nt<GENH>(hgb, t0, GENH, gen_w2, o0, GENH, 0, sm.ab.As, sm.ab.Bs, acc);

  const int tid = threadIdx.x, lane = tid & 63, wave = tid >> 6;
  // stage x tile [128 t x 128 d] bf16, row stride 132 (pad kills conflicts)
#pragma unroll
  for (int i = 0; i < 8; ++i) {
    int q = i * 256 + tid;          // 8-short chunks, 2048 total
    int row = q >> 4, c = q & 15;
    const unsigned short* src = xb + (t0 + (size_t)row) * DIMX + d0 + c * 8;
    ushort4 v0 = *(const ushort4*)src;
    ushort4 v1 = *(const ushort4*)(src + 4);
    unsigned short* dst = sm.ep.Xs + row * 132 + c * 8;
    *(ushort4*)dst = v0;
    *(ushort4*)(dst + 4) = v1;
  }
  if (tid < 128) sm.ep.upart[tid] = 0.f;
  __syncthreads();

  const int m0 = (wave >> 1) * 64, n0 = (wave & 1) * 64;
  float gb[4];
#pragma unroll
  for (int nf = 0; nf < 4; ++nf)
    gb[nf] = gen_b2[o0 + n0 + nf * 16 + (lane & 15)];
#pragma unroll
  for (int mf = 0; mf < 4; ++mf) {
    int rb = m0 + mf * 16 + ((lane >> 4) << 2);
#pragma unroll
    for (int rg = 0; rg < 4; ++rg) {
      int trow = rb + rg;
      float val = 0.f;
#pragma unroll
      for (int nf = 0; nf < 4; ++nf) {
        int col = n0 + nf * 16 + (lane & 15);
        val += (acc[mf][nf][rg] + gb[nf]) * bf2f(sm.ep.Xs[trow * 132 + col]);
      }
      val += __shfl_xor(val, 1);
      val += __shfl_xor(val, 2);
      val += __shfl_xor(val, 4);
      val += __shfl_xor(val, 8);
      if ((lane & 15) == 0) atomicAdd(&sm.ep.upart[trow], val);
    }
  }
  __syncthreads();
  if (tid < 128) atomicAdd(&u[(t0 + tid) * 128 + j], sm.ep.upart[tid]);
}

// ---------------------------------------------------------------------------
// h_mem = silu(u1) * u2
// ---------------------------------------------------------------------------
__global__ void hmem_kernel(const float* __restrict__ u, float* __restrict__ hm) {
  int i = blockIdx.x * 256 + threadIdx.x;  // 65536
  int t = i >> 6, r = i & 63;
  float u1 = u[t * 128 + r], u2 = u[t * 128 + 64 + r];
  hm[i] = silu_f(u1) * u2;
}

// ---------------------------------------------------------------------------
// memy: fused path 3. Block = [128 tok x 128 o3] (o3 = d*64+r -> 2 full d's),
// epilogue contracts against h_mem (LDS, stride-66 pad) over r and does
// y += g * y_mem. gen_b2 folded in.
// ---------------------------------------------------------------------------
union SmemY {
  struct { unsigned short As[8192], Bs[8192]; } ab;
  struct { float Hs[128 * 66]; float ypart[256]; } ep;
};

__global__ __launch_bounds__(256) void memy_kernel(
    const unsigned short* __restrict__ hgb, const float* __restrict__ gen_w2,
    const float* __restrict__ gen_b2, const float* __restrict__ hmem,
    const float* __restrict__ mem_gate, float* __restrict__ y) {
  __shared__ SmemY sm;
  const int bx = blockIdx.x;
  const int ob = bx & 255, tb = bx >> 8;
  const size_t brow0 = (size_t)O3BASE + (size_t)ob * 128;
  const size_t t0 = (size_t)tb * 128;

  f32x4 acc[4][4];
  zero_acc(acc);
  mfma_tile_nt<GENH>(hgb, t0, GENH, gen_w2, brow0, GENH, 0, sm.ab.As, sm.ab.Bs, acc);

  const int tid = threadIdx.x, lane = tid & 63, wave = tid >> 6;
  // stage h_mem tile [128 t x 64 r] f32, row stride 66
#pragma unroll
  for (int i = 0; i < 8; ++i) {
    int q = i * 256 + tid;          // float4 chunks, 2048 total
    int row = q >> 4, c = q & 15;
    float4 v = *(const float4*)(hmem + (t0 + (size_t)row) * RR + c * 4);
    float* dst = sm.ep.Hs + row * 66 + c * 4;
    *(float2*)dst = make_float2(v.x, v.y);
    *(float2*)(dst + 2) = make_float2(v.z, v.w);
  }
  sm.ep.ypart[tid] = 0.f;
  __syncthreads();

  const int m0 = (wave >> 1) * 64, n0 = (wave & 1) * 64;
  const int dsel = n0 >> 6;         // which of the 2 d's this wave covers
  float gb[4];
#pragma unroll
  for (int nf = 0; nf < 4; ++nf)
    gb[nf] = gen_b2[brow0 + n0 + nf * 16 + (lane & 15)];
#pragma unroll
  for (int mf = 0; mf < 4; ++mf) {
    int rb = m0 + mf * 16 + ((lane >> 4) << 2);
#pragma unroll
    for (int rg = 0; rg < 4; ++rg) {
      int trow = rb + rg;
      float val = 0.f;
#pragma unroll
      for (int nf = 0; nf < 4; ++nf) {
        int r = nf * 16 + (lane & 15);
        val += (acc[mf][nf][rg] + gb[nf]) * sm.ep.Hs[trow * 66 + r];
      }
      val += __shfl_xor(val, 1);
      val += __shfl_xor(val, 2);
      val += __shfl_xor(val, 4);
      val += __shfl_xor(val, 8);
      if ((lane & 15) == 0) atomicAdd(&sm.ep.ypart[trow * 2 + dsel], val);
    }
  }
  __syncthreads();
  {
    float g = 1.f / (1.f + __expf(-mem_gate[0]));
    int t = tid >> 1, di = tid & 1;
    size_t gi = (t0 + (size_t)t) * DIMX + (size_t)ob * 2 + di;
    y[gi] += g * sm.ep.ypart[t * 2 + di];
  }
}

// ---------------------------------------------------------------------------
extern "C" void kernel_launch(void* const* d_in, const int* in_sizes, int n_in,
                              void* d_out, int out_size, void* d_ws, size_t ws_size,
                              hipStream_t stream) {
  const float* x        = (const float*)d_in[0];
  const float* m_tok    = (const float*)d_in[1];
  const float* W1       = (const float*)d_in[2];
  const float* W2       = (const float*)d_in[3];
  const float* W3       = (const float*)d_in[4];
  const float* b1       = (const float*)d_in[5];
  const float* b2       = (const float*)d_in[6];
  const float* b3       = (const float*)d_in[7];
  const float* gen_w1   = (const float*)d_in[8];
  const float* gen_b1   = (const float*)d_in[9];
  const float* gen_w2   = (const float*)d_in[10];
  const float* gen_b2   = (const float*)d_in[11];
  const float* mem_gate = (const float*)d_in[12];
  float* y = (float*)d_out;

  char* ws = (char*)d_ws;
  unsigned short* xb  = (unsigned short*)(ws);                    // 1 MB
  unsigned short* hgb = (unsigned short*)(ws + (1u << 20));       // 1 MB
  float* x1 = (float*)(ws + (2u << 20));                          // 8 MB
  float* x2 = (float*)(ws + (10u << 20));                         // 8 MB
  unsigned short* hb = (unsigned short*)(ws + (18u << 20));       // 4 MB
  float* u  = (float*)(ws + (22u << 20));                         // 512 KB
  float* hm = (float*)(ws + (22u << 20) + (512u << 10));          // 256 KB

  // prep: hg (bf16) + x cast (bf16)
  prep_kernel<<<256, 256, 0, stream>>>(x, m_tok, gen_w1, gen_b1, xb, hgb);
  // zero accumulators (ws/out are poisoned each call)
  hipMemsetAsync(u, 0, TOK * 128 * sizeof(float), stream);
  hipMemsetAsync(y, 0, (size_t)out_size * sizeof(float), stream);

  // base FFN
  gemm_nt_kernel<HID, DIMX, DIMX, false><<<dim3(16 * 8), 256, 0, stream>>>(xb, W1, b1, x1);
  gemm_nt_kernel<HID, DIMX, DIMX, false><<<dim3(16 * 8), 256, 0, stream>>>(xb, W2, b2, x2);
  silu_mul_kernel<<<(TOK * HID) / 256, 256, 0, stream>>>(x1, x2, hb);
  gemm_nt_kernel<DIMX, HID, DIMX, true><<<dim3(4 * 8, 4), 256, 0, stream>>>(hb, W3, b3, y);

  // memory path
  memuv_kernel<<<512 * 8, 256, 0, stream>>>(hgb, gen_w2, gen_b2, xb, u);
  hmem_kernel<<<(TOK * RR) / 256, 256, 0, stream>>>(u, hm);
  memy_kernel<<<256 * 8, 256, 0, stream>>>(hgb, gen_w2, gen_b2, hm, mem_gate, y);
}

// Round 2
// 581.711 us; speedup vs baseline: 1.0500x; 1.0500x over previous
//
#include <hip/hip_runtime.h>
#include <cstdint>
#include <cstddef>

// Problem dims (fixed)
#define TOK   1024   // B*T
#define DIMX  512
#define HID   2048
#define DM    256
#define GENH  512
#define RR    64
#define O3BASE 65536 // start row of path-3 block in gen_w2 (2*R*DIM)

typedef __bf16 bf16x8 __attribute__((ext_vector_type(8)));
typedef float  f32x4  __attribute__((ext_vector_type(4)));

__device__ __forceinline__ unsigned short f2bf(float f) {
  union { float f; uint32_t u; } v; v.f = f;
  return (unsigned short)((v.u + 0x7fffu + ((v.u >> 16) & 1u)) >> 16);
}
__device__ __forceinline__ float bf2f(unsigned short h) {
  union { uint32_t u; float f; } v; v.u = (uint32_t)h << 16;
  return v.f;
}
__device__ __forceinline__ float silu_f(float x) { return x / (1.f + __expf(-x)); }

__device__ __forceinline__ void async_copy16(const void* g, void* l) {
  __builtin_amdgcn_global_load_lds(
      (const __attribute__((address_space(1))) void*)g,
      (__attribute__((address_space(3))) void*)l, 16, 0, 0);
}

// ---------------------------------------------------------------------------
// f32 -> bf16 cast, 8 elems/thread (32B read / 16B write per lane)
// ---------------------------------------------------------------------------
__global__ __launch_bounds__(256) void cast_bf16_kernel(
    const float* __restrict__ src, unsigned short* __restrict__ dst) {
  size_t i = ((size_t)blockIdx.x * 256 + threadIdx.x) * 8;
  float4 v0 = *(const float4*)(src + i);
  float4 v1 = *(const float4*)(src + i + 4);
  ushort4 h0, h1;
  h0.x = f2bf(v0.x); h0.y = f2bf(v0.y); h0.z = f2bf(v0.z); h0.w = f2bf(v0.w);
  h1.x = f2bf(v1.x); h1.y = f2bf(v1.y); h1.z = f2bf(v1.z); h1.w = f2bf(v1.w);
  *(ushort4*)(dst + i)     = h0;
  *(ushort4*)(dst + i + 4) = h1;
}

// ---------------------------------------------------------------------------
// Stage one [128 x 64] bf16 tile into LDS via global_load_lds width=16,
// fetch-side XOR swizzle (chunk' = chunk ^ (row&7)) -> bank-conflict-free
// ds_read_b128 on the compute side.
// ---------------------------------------------------------------------------
__device__ __forceinline__ void stage_tile(
    const unsigned short* __restrict__ base, size_t row0, int stride, int kofs,
    unsigned short* Ls, int wave, int lane) {
#pragma unroll
  for (int j = 0; j < 4; ++j) {
    int s   = wave * 256 + j * 64 + lane;   // linear 16B slot 0..1023
    int row = s >> 3;
    int kc  = (s & 7) ^ (row & 7);          // fetch-side swizzle
    const unsigned short* g = base + (row0 + (size_t)row) * (size_t)stride + kofs + kc * 8;
    async_copy16(g, (char*)Ls + wave * 4096 + j * 1024);
  }
}

// ---------------------------------------------------------------------------
// Core: C[128 x 128] tile of A(bf16, row-major, K-contig) @ B(bf16, row-major,
// K-contig)^T via mfma_f32_16x16x32_bf16. 4 waves in 2x2. Both operands
// staged with global_load_lds width=16. Ends with __syncthreads().
// ---------------------------------------------------------------------------
template<int KLEN>
__device__ __forceinline__ void mfma_tile_nt(
    const unsigned short* __restrict__ Abf, size_t a_row0, int astride,
    const unsigned short* __restrict__ Bbf, size_t b_row0, int bstride, int k0,
    unsigned short* As, unsigned short* Bs, f32x4 (&acc)[4][4]) {
  const int tid  = threadIdx.x;
  const int lane = tid & 63;
  const int wave = tid >> 6;
  const int m0 = (wave >> 1) * 64, n0 = (wave & 1) * 64;

  for (int kk = 0; kk < KLEN; kk += 64) {
    stage_tile(Abf, a_row0, astride, k0 + kk, As, wave, lane);
    stage_tile(Bbf, b_row0, bstride, k0 + kk, Bs, wave, lane);
    __syncthreads();
#pragma unroll
    for (int ks = 0; ks < 2; ++ks) {
      int cbase = ks * 4 + (lane >> 4);
      int koff  = (cbase ^ (lane & 7)) * 8;   // row&7 == lane&7 for all frags
      bf16x8 a[4], b[4];
#pragma unroll
      for (int mf = 0; mf < 4; ++mf)
        a[mf] = *(const bf16x8*)(As + (m0 + mf * 16 + (lane & 15)) * 64 + koff);
#pragma unroll
      for (int nf = 0; nf < 4; ++nf)
        b[nf] = *(const bf16x8*)(Bs + (n0 + nf * 16 + (lane & 15)) * 64 + koff);
#pragma unroll
      for (int mf = 0; mf < 4; ++mf)
#pragma unroll
        for (int nf = 0; nf < 4; ++nf)
          acc[mf][nf] = __builtin_amdgcn_mfma_f32_16x16x32_bf16(
              a[mf], b[nf], acc[mf][nf], 0, 0, 0);
    }
    __syncthreads();
  }
}

__device__ __forceinline__ void zero_acc(f32x4 (&acc)[4][4]) {
#pragma unroll
  for (int i = 0; i < 4; ++i)
#pragma unroll
    for (int j = 0; j < 4; ++j) {
      f32x4 z = {0.f, 0.f, 0.f, 0.f};
      acc[i][j] = z;
    }
}

// ---------------------------------------------------------------------------
// prep: hg = silu(m_tok @ gen_w1^T + gen_b1) -> bf16; x -> bf16. 4 tokens/blk.
// ---------------------------------------------------------------------------
__global__ __launch_bounds__(256) void prep_kernel(
    const float* __restrict__ x, const float* __restrict__ m_tok,
    const float* __restrict__ gen_w1, const float* __restrict__ gen_b1,
    unsigned short* __restrict__ xb, unsigned short* __restrict__ hgb) {
  __shared__ float mt[4 * DM];
  const int tid = threadIdx.x;
  const size_t t0 = (size_t)blockIdx.x * 4;
#pragma unroll
  for (int k = 0; k < 4; ++k) mt[k * 256 + tid] = m_tok[t0 * DM + k * 256 + tid];
#pragma unroll
  for (int k = 0; k < 8; ++k) {
    size_t idx = t0 * DIMX + k * 256 + tid;
    xb[idx] = f2bf(x[idx]);
  }
  __syncthreads();
#pragma unroll
  for (int hh = 0; hh < 2; ++hh) {
    int h = hh * 256 + tid;
    float a0, a1, a2, a3;
    a0 = a1 = a2 = a3 = gen_b1[h];
    const float* wr = gen_w1 + (size_t)h * DM;
    for (int d = 0; d < DM; d += 4) {
      float4 w = *(const float4*)(wr + d);
      a0 += w.x * mt[d]       + w.y * mt[d + 1]       + w.z * mt[d + 2]       + w.w * mt[d + 3];
      a1 += w.x * mt[256 + d] + w.y * mt[256 + d + 1] + w.z * mt[256 + d + 2] + w.w * mt[256 + d + 3];
      a2 += w.x * mt[512 + d] + w.y * mt[512 + d + 1] + w.z * mt[512 + d + 2] + w.w * mt[512 + d + 3];
      a3 += w.x * mt[768 + d] + w.y * mt[768 + d + 1] + w.z * mt[768 + d + 2] + w.w * mt[768 + d + 3];
    }
    hgb[(t0 + 0) * GENH + h] = f2bf(silu_f(a0));
    hgb[(t0 + 1) * GENH + h] = f2bf(silu_f(a1));
    hgb[(t0 + 2) * GENH + h] = f2bf(silu_f(a2));
    hgb[(t0 + 3) * GENH + h] = f2bf(silu_f(a3));
  }
}

// ---------------------------------------------------------------------------
// Generic NT GEMM: C[tok, N] = A_bf16[tok, KFULL] @ B_bf16[N, KFULL]^T + bias.
// SPLIT: grid.y splits K, atomicAdd into pre-zeroed C (bias from k-slice 0).
// ---------------------------------------------------------------------------
template<int N, int KFULL, int KTILE, bool SPLIT>
__global__ __launch_bounds__(256) void gemm_nt_kernel(
    const unsigned short* __restrict__ A, const unsigned short* __restrict__ B,
    const float* __restrict__ bias, float* __restrict__ C) {
  __shared__ unsigned short As[8192];
  __shared__ unsigned short Bs[8192];
  constexpr int NB = N / 128;
  const int ob = blockIdx.x % NB, tb = blockIdx.x / NB;
  const size_t o0 = (size_t)ob * 128, t0 = (size_t)tb * 128;
  const int k0 = SPLIT ? blockIdx.y * KTILE : 0;
  f32x4 acc[4][4];
  zero_acc(acc);
  mfma_tile_nt<KTILE>(A, t0, KFULL, B, o0, KFULL, k0, As, Bs, acc);

  const int tid = threadIdx.x, lane = tid & 63, wave = tid >> 6;
  const int m0 = (wave >> 1) * 64, n0 = (wave & 1) * 64;
#pragma unroll
  for (int nf = 0; nf < 4; ++nf) {
    int n = n0 + nf * 16 + (lane & 15);
    float bv = (!SPLIT || k0 == 0) ? bias[o0 + n] : 0.f;
#pragma unroll
    for (int mf = 0; mf < 4; ++mf) {
      int mb = m0 + mf * 16 + ((lane >> 4) << 2);
#pragma unroll
      for (int rg = 0; rg < 4; ++rg) {
        size_t idx = (t0 + mb + rg) * (size_t)N + o0 + n;
        float v = acc[mf][nf][rg] + bv;
        if (SPLIT) atomicAdd(&C[idx], v);
        else C[idx] = v;
      }
    }
  }
}

// ---------------------------------------------------------------------------
// h_base = bf16(silu(x1) * x2)
// ---------------------------------------------------------------------------
__global__ void silu_mul_kernel(const float* __restrict__ a,
                                const float* __restrict__ b,
                                unsigned short* __restrict__ o) {
  size_t i = (size_t)blockIdx.x * 256 + threadIdx.x;
  o[i] = f2bf(silu_f(a[i]) * b[i]);
}

// ---------------------------------------------------------------------------
// memuv: fused paths 1&2. Block = [128 tok x 128 o] tile of w (o in one r),
// epilogue contracts against x (bf16, LDS pad-132 -> conflict-free) and
// shuffle-reduces to u[t, j] (j = 0..127: u1 r | u2 r). gen_b2 folded in.
// Grid: tb INNER (bx&7) so concurrent blocks share the gen_w2 strip in L2/L3.
// ---------------------------------------------------------------------------
union SmemUV {
  struct { unsigned short As[8192], Bs[8192]; } ab;
  struct { unsigned short Xs[128 * 132]; float upart[128]; } ep;
};

__global__ __launch_bounds__(256) void memuv_kernel(
    const unsigned short* __restrict__ hgb, const unsigned short* __restrict__ w2b,
    const float* __restrict__ gen_b2, const unsigned short* __restrict__ xb,
    float* __restrict__ u) {
  __shared__ SmemUV sm;
  const int bx = blockIdx.x;
  const int tb = bx & 7, ob = bx >> 3;
  const size_t o0 = (size_t)ob * 128, t0 = (size_t)tb * 128;
  const int j  = ob >> 2;           // u column (0..127)
  const int d0 = (ob & 3) * 128;    // d-range within the r row

  f32x4 acc[4][4];
  zero_acc(acc);
  mfma_tile_nt<GENH>(hgb, t0, GENH, w2b, o0, GENH, 0, sm.ab.As, sm.ab.Bs, acc);

  const int tid = threadIdx.x, lane = tid & 63, wave = tid >> 6;
  // stage x tile [128 t x 128 d] bf16, row stride 132 (pad kills conflicts)
#pragma unroll
  for (int i = 0; i < 8; ++i) {
    int q = i * 256 + tid;          // 8-short chunks, 2048 total
    int row = q >> 4, c = q & 15;
    const unsigned short* src = xb + (t0 + (size_t)row) * DIMX + d0 + c * 8;
    ushort4 v0 = *(const ushort4*)src;
    ushort4 v1 = *(const ushort4*)(src + 4);
    unsigned short* dst = sm.ep.Xs + row * 132 + c * 8;
    *(ushort4*)dst = v0;
    *(ushort4*)(dst + 4) = v1;
  }
  if (tid < 128) sm.ep.upart[tid] = 0.f;
  __syncthreads();

  const int m0 = (wave >> 1) * 64, n0 = (wave & 1) * 64;
  float gb[4];
#pragma unroll
  for (int nf = 0; nf < 4; ++nf)
    gb[nf] = gen_b2[o0 + n0 + nf * 16 + (lane & 15)];
#pragma unroll
  for (int mf = 0; mf < 4; ++mf) {
    int rb = m0 + mf * 16 + ((lane >> 4) << 2);
#pragma unroll
    for (int rg = 0; rg < 4; ++rg) {
      int trow = rb + rg;
      float val = 0.f;
#pragma unroll
      for (int nf = 0; nf < 4; ++nf) {
        int col = n0 + nf * 16 + (lane & 15);
        val += (acc[mf][nf][rg] + gb[nf]) * bf2f(sm.ep.Xs[trow * 132 + col]);
      }
      val += __shfl_xor(val, 1);
      val += __shfl_xor(val, 2);
      val += __shfl_xor(val, 4);
      val += __shfl_xor(val, 8);
      if ((lane & 15) == 0) atomicAdd(&sm.ep.upart[trow], val);
    }
  }
  __syncthreads();
  if (tid < 128) atomicAdd(&u[(t0 + tid) * 128 + j], sm.ep.upart[tid]);
}

// ---------------------------------------------------------------------------
// h_mem = silu(u1) * u2
// ---------------------------------------------------------------------------
__global__ void hmem_kernel(const float* __restrict__ u, float* __restrict__ hm) {
  int i = blockIdx.x * 256 + threadIdx.x;  // 65536
  int t = i >> 6, r = i & 63;
  float u1 = u[t * 128 + r], u2 = u[t * 128 + 64 + r];
  hm[i] = silu_f(u1) * u2;
}

// ---------------------------------------------------------------------------
// memy: fused path 3. Block = [128 tok x 128 o3] (o3 = d*64+r -> 2 full d's),
// epilogue contracts against h_mem (LDS, stride-66 pad) over r and does
// y += g * y_mem. gen_b2 folded in. tb inner for gen_w2 strip sharing.
// ---------------------------------------------------------------------------
union SmemY {
  struct { unsigned short As[8192], Bs[8192]; } ab;
  struct { float Hs[128 * 66]; float ypart[256]; } ep;
};

__global__ __launch_bounds__(256) void memy_kernel(
    const unsigned short* __restrict__ hgb, const unsigned short* __restrict__ w2b,
    const float* __restrict__ gen_b2, const float* __restrict__ hmem,
    const float* __restrict__ mem_gate, float* __restrict__ y) {
  __shared__ SmemY sm;
  const int bx = blockIdx.x;
  const int tb = bx & 7, ob = bx >> 3;
  const size_t brow0 = (size_t)O3BASE + (size_t)ob * 128;
  const size_t t0 = (size_t)tb * 128;

  f32x4 acc[4][4];
  zero_acc(acc);
  mfma_tile_nt<GENH>(hgb, t0, GENH, w2b, brow0, GENH, 0, sm.ab.As, sm.ab.Bs, acc);

  const int tid = threadIdx.x, lane = tid & 63, wave = tid >> 6;
  // stage h_mem tile [128 t x 64 r] f32, row stride 66
#pragma unroll
  for (int i = 0; i < 8; ++i) {
    int q = i * 256 + tid;          // float4 chunks, 2048 total
    int row = q >> 4, c = q & 15;
    float4 v = *(const float4*)(hmem + (t0 + (size_t)row) * RR + c * 4);
    float* dst = sm.ep.Hs + row * 66 + c * 4;
    *(float2*)dst = make_float2(v.x, v.y);
    *(float2*)(dst + 2) = make_float2(v.z, v.w);
  }
  sm.ep.ypart[tid] = 0.f;
  __syncthreads();

  const int m0 = (wave >> 1) * 64, n0 = (wave & 1) * 64;
  const int dsel = n0 >> 6;         // which of the 2 d's this wave covers
  float gb[4];
#pragma unroll
  for (int nf = 0; nf < 4; ++nf)
    gb[nf] = gen_b2[brow0 + n0 + nf * 16 + (lane & 15)];
#pragma unroll
  for (int mf = 0; mf < 4; ++mf) {
    int rb = m0 + mf * 16 + ((lane >> 4) << 2);
#pragma unroll
    for (int rg = 0; rg < 4; ++rg) {
      int trow = rb + rg;
      float val = 0.f;
#pragma unroll
      for (int nf = 0; nf < 4; ++nf) {
        int r = nf * 16 + (lane & 15);
        val += (acc[mf][nf][rg] + gb[nf]) * sm.ep.Hs[trow * 66 + r];
      }
      val += __shfl_xor(val, 1);
      val += __shfl_xor(val, 2);
      val += __shfl_xor(val, 4);
      val += __shfl_xor(val, 8);
      if ((lane & 15) == 0) atomicAdd(&sm.ep.ypart[trow * 2 + dsel], val);
    }
  }
  __syncthreads();
  {
    float g = 1.f / (1.f + __expf(-mem_gate[0]));
    int t = tid >> 1, di = tid & 1;
    size_t gi = (t0 + (size_t)t) * DIMX + (size_t)ob * 2 + di;
    y[gi] += g * sm.ep.ypart[t * 2 + di];
  }
}

// ---------------------------------------------------------------------------
extern "C" void kernel_launch(void* const* d_in, const int* in_sizes, int n_in,
                              void* d_out, int out_size, void* d_ws, size_t ws_size,
                              hipStream_t stream) {
  const float* x        = (const float*)d_in[0];
  const float* m_tok    = (const float*)d_in[1];
  const float* W1       = (const float*)d_in[2];
  const float* W2       = (const float*)d_in[3];
  const float* W3       = (const float*)d_in[4];
  const float* b1       = (const float*)d_in[5];
  const float* b2       = (const float*)d_in[6];
  const float* b3       = (const float*)d_in[7];
  const float* gen_w1   = (const float*)d_in[8];
  const float* gen_b1   = (const float*)d_in[9];
  const float* gen_w2   = (const float*)d_in[10];
  const float* gen_b2   = (const float*)d_in[11];
  const float* mem_gate = (const float*)d_in[12];
  float* y = (float*)d_out;

  char* ws = (char*)d_ws;
#define MB(v) ((size_t)(v) << 20)
  unsigned short* xb  = (unsigned short*)(ws);             // 1 MB
  unsigned short* hgb = (unsigned short*)(ws + MB(1));     // 1 MB
  float* x1 = (float*)(ws + MB(2));                        // 8 MB
  float* x2 = (float*)(ws + MB(10));                       // 8 MB
  unsigned short* hb  = (unsigned short*)(ws + MB(18));    // 4 MB
  float* u  = (float*)(ws + MB(22));                       // 512 KB
  float* hm = (float*)(ws + MB(22) + (512u << 10));        // 256 KB
  unsigned short* W1b = (unsigned short*)(ws + MB(23));    // 2 MB
  unsigned short* W2b = (unsigned short*)(ws + MB(25));    // 2 MB
  unsigned short* W3b = (unsigned short*)(ws + MB(27));    // 2 MB
  unsigned short* w2b = (unsigned short*)(ws + MB(29));    // 96 MB
#undef MB

  // prep: hg (bf16) + x cast (bf16)
  prep_kernel<<<256, 256, 0, stream>>>(x, m_tok, gen_w1, gen_b1, xb, hgb);
  // weight casts to bf16
  cast_bf16_kernel<<<24576, 256, 0, stream>>>(gen_w2, w2b);
  cast_bf16_kernel<<<512, 256, 0, stream>>>(W1, W1b);
  cast_bf16_kernel<<<512, 256, 0, stream>>>(W2, W2b);
  cast_bf16_kernel<<<512, 256, 0, stream>>>(W3, W3b);
  // zero accumulators (ws/out are poisoned each call)
  hipMemsetAsync(u, 0, TOK * 128 * sizeof(float), stream);
  hipMemsetAsync(y, 0, (size_t)out_size * sizeof(float), stream);

  // base FFN
  gemm_nt_kernel<HID, DIMX, DIMX, false><<<dim3(16 * 8), 256, 0, stream>>>(xb, W1b, b1, x1);
  gemm_nt_kernel<HID, DIMX, DIMX, false><<<dim3(16 * 8), 256, 0, stream>>>(xb, W2b, b2, x2);
  silu_mul_kernel<<<(TOK * HID) / 256, 256, 0, stream>>>(x1, x2, hb);
  gemm_nt_kernel<DIMX, HID, DIMX, true><<<dim3(4 * 8, 4), 256, 0, stream>>>(hb, W3b, b3, y);

  // memory path
  memuv_kernel<<<512 * 8, 256, 0, stream>>>(hgb, w2b, gen_b2, xb, u);
  hmem_kernel<<<(TOK * RR) / 256, 256, 0, stream>>>(u, hm);
  memy_kernel<<<256 * 8, 256, 0, stream>>>(hgb, w2b, gen_b2, hm, mem_gate, y);
}